// Round 10
// baseline (916.853 us; speedup 1.0000x reference)
//
#include <hip/hip_runtime.h>
#include <math.h>

#define N_NODES   100000
#define N_EDGES   1600000
#define D_FEAT    64
#define N_CH      64

#define SELU_SCALE 1.0507009873554805f
#define SELU_ALPHA 1.6732632423543772f

// ------------------------- bucket config -------------------------
#define BROWS      128                                   // rows per bucket
#define NBUCK      ((N_NODES + BROWS - 1) / BROWS)       // 782
#define BIN_BLOCKS 256
#define EPB        (N_EDGES / BIN_BLOCKS)                // 6250 edges/block (exact)
#define BIN_ITERS  ((EPB + 255) / 256)                   // 25

// ------------------------- gemm config -------------------------
#define G_ROWS_PER_WAVE 16
#define G_ROWS_PER_BLOCK (4 * G_ROWS_PER_WAVE)   // 64
#define NB_GEMM  ((N_NODES + G_ROWS_PER_BLOCK - 1) / G_ROWS_PER_BLOCK)  // 1563

// ===========================================================================
// GEMM body: h = features @ W + bias.  Lane = channel; W column in 64 VGPRs;
// feature row via wave-uniform scalar loads.
// ===========================================================================
__device__ __forceinline__ void gemm_body(
    int gb,
    const float* __restrict__ feat,
    const float* __restrict__ W,
    const float* __restrict__ bias,
    float* __restrict__ h)
{
    int lane = threadIdx.x & 63;
    int wave = threadIdx.x >> 6;

    float Wc[D_FEAT];
    #pragma unroll
    for (int k = 0; k < D_FEAT; ++k) Wc[k] = W[k * N_CH + lane];
    float b = bias[lane];

    int row0 = (gb * 4 + wave) * G_ROWS_PER_WAVE;
    for (int r = 0; r < G_ROWS_PER_WAVE; ++r) {
        int row = row0 + r;
        if (row >= N_NODES) return;
        int row_u = __builtin_amdgcn_readfirstlane(row);
        const float* frow = feat + (size_t)row_u * D_FEAT;
        float a0 = b, a1 = 0.f, a2 = 0.f, a3 = 0.f;
        #pragma unroll
        for (int k = 0; k < D_FEAT; k += 4) {
            a0 = fmaf(frow[k + 0], Wc[k + 0], a0);
            a1 = fmaf(frow[k + 1], Wc[k + 1], a1);
            a2 = fmaf(frow[k + 2], Wc[k + 2], a2);
            a3 = fmaf(frow[k + 3], Wc[k + 3], a3);
        }
        h[row * N_CH + lane] = (a0 + a1) + (a2 + a3);
    }
}

// ===========================================================================
// Bucket build pass 1: global bucket histogram via per-block LDS histogram.
// 782 global atomics per block instead of 1.6M global atomic-returns.
// ===========================================================================
__global__ __launch_bounds__(256) void zero_bcount_kernel(int* __restrict__ bcount)
{
    for (int b = threadIdx.x; b < NBUCK; b += 256) bcount[b] = 0;
}

__global__ __launch_bounds__(256) void hist_kernel(
    const int* __restrict__ rows, int* __restrict__ bcount)
{
    __shared__ int hist[NBUCK];
    int tid = threadIdx.x;
    for (int b = tid; b < NBUCK; b += 256) hist[b] = 0;
    __syncthreads();
    int base = blockIdx.x * EPB;
    for (int it = 0; it < BIN_ITERS; ++it) {
        int e = base + it * 256 + tid;
        if (e < base + EPB) atomicAdd(&hist[rows[e] >> 7], 1);
    }
    __syncthreads();
    for (int b = tid; b < NBUCK; b += 256) {
        int c = hist[b];
        if (c) atomicAdd(&bcount[b], c);
    }
}

// ===========================================================================
// Bucket build pass 2: exclusive scan of 782 bucket counts (single block).
// ===========================================================================
__global__ __launch_bounds__(1024) void scan_buckets_kernel(
    const int* __restrict__ bcount, int* __restrict__ bstart,
    int* __restrict__ gcursor)
{
    __shared__ int lds[1024];
    int t = threadIdx.x;
    lds[t] = (t < NBUCK) ? bcount[t] : 0;
    __syncthreads();
    for (int off = 1; off < 1024; off <<= 1) {
        int y = (t >= off) ? lds[t - off] : 0;
        __syncthreads();
        lds[t] += y;
        __syncthreads();
    }
    int excl = (t > 0) ? lds[t - 1] : 0;
    if (t < NBUCK) { bstart[t] = excl; gcursor[t] = excl; }
    if (t == 0) bstart[NBUCK] = N_EDGES;
}

// ===========================================================================
// Bucket build pass 3 (fused with GEMM): block reserves per-bucket space
// (one atomic-return per touched bucket), LDS assigns local slots, records
// written CONSECUTIVELY within each bucket region -> ~full 64B lines.
// pack64: [63:32]=val bits, [24:17]=localrow, [16:0]=col.
// ===========================================================================
__device__ __forceinline__ void binscatter_body(
    int blk,
    const int* __restrict__ rows, const int* __restrict__ cols,
    const float* __restrict__ vals,
    int* __restrict__ gcursor, unsigned long long* __restrict__ pack)
{
    __shared__ int hist[NBUCK];    // phase A: count; phase B: local cursor
    __shared__ int lbase[NBUCK];
    int tid = threadIdx.x;
    for (int b = tid; b < NBUCK; b += 256) hist[b] = 0;
    __syncthreads();

    int base = blk * EPB;
    int rowreg[BIN_ITERS];
    #pragma unroll
    for (int it = 0; it < BIN_ITERS; ++it) {
        int e = base + it * 256 + tid;
        rowreg[it] = (e < base + EPB) ? rows[e] : -1;
        if (rowreg[it] >= 0) atomicAdd(&hist[rowreg[it] >> 7], 1);
    }
    __syncthreads();
    for (int b = tid; b < NBUCK; b += 256) {
        int c = hist[b];
        lbase[b] = c ? atomicAdd(&gcursor[b], c) : 0;
    }
    __syncthreads();
    for (int b = tid; b < NBUCK; b += 256) hist[b] = 0;
    __syncthreads();
    #pragma unroll
    for (int it = 0; it < BIN_ITERS; ++it) {
        int r = rowreg[it];
        if (r >= 0) {
            int e = base + it * 256 + tid;
            int b = r >> 7;
            int slot = lbase[b] + atomicAdd(&hist[b], 1);
            unsigned long long p =
                ((unsigned long long)__float_as_uint(vals[e]) << 32)
                | ((unsigned)(r & (BROWS - 1)) << 17) | (unsigned)cols[e];
            __builtin_nontemporal_store(p, &pack[slot]);
        }
    }
}

__global__ __launch_bounds__(256) void binscatter_gemm_kernel(
    const int* __restrict__ rows, const int* __restrict__ cols,
    const float* __restrict__ vals,
    int* __restrict__ gcursor, unsigned long long* __restrict__ pack,
    const float* __restrict__ feat, const float* __restrict__ W,
    const float* __restrict__ bias, float* __restrict__ h)
{
    if (blockIdx.x < BIN_BLOCKS) {
        binscatter_body(blockIdx.x, rows, cols, vals, gcursor, pack);
    } else {
        gemm_body(blockIdx.x - BIN_BLOCKS, feat, W, bias, h);
    }
}

// ===========================================================================
// Bucket aggregate: one block per bucket; 32 KB LDS acc[128][64] (f32).
// Edges read coalesced FULL-wave; shfl-broadcast 4 edges in flight;
// gather h[col][lane]; ds_add_f32 into acc.  Fused skip+SeLU epilogue.
// ===========================================================================
__global__ __launch_bounds__(256) void bucket_agg_kernel(
    const int* __restrict__ bstart,
    const unsigned long long* __restrict__ pack,
    const float* __restrict__ h,
    const float* __restrict__ skip,
    float* __restrict__ out)
{
    __shared__ float acc[BROWS][N_CH];   // 32 KB -> up to 5 blocks/CU
    int tid  = threadIdx.x;
    int lane = tid & 63;
    int wv   = tid >> 6;

    float* accf = &acc[0][0];
    for (int i = tid; i < (BROWS * N_CH) / 4; i += 256)
        reinterpret_cast<float4*>(accf)[i] = make_float4(0.f, 0.f, 0.f, 0.f);
    __syncthreads();

    int s = bstart[blockIdx.x];
    int e = bstart[blockIdx.x + 1];

    for (int j = s + wv * 64; j < e; j += 256) {
        int cnt = e - j;
        if (cnt > 64) cnt = 64;
        unsigned long long p = 0ull;          // val=0 padding -> adds 0.0f
        if (lane < cnt) p = pack[j + lane];   // coalesced 512B
        unsigned plo = (unsigned)p;
        unsigned phi = (unsigned)(p >> 32);
        int pc = (cnt + 3) & ~3;
        for (int k = 0; k < pc; k += 4) {
            unsigned l0 = __shfl((int)plo, k + 0, 64); unsigned v0 = __shfl((int)phi, k + 0, 64);
            unsigned l1 = __shfl((int)plo, k + 1, 64); unsigned v1 = __shfl((int)phi, k + 1, 64);
            unsigned l2 = __shfl((int)plo, k + 2, 64); unsigned v2 = __shfl((int)phi, k + 2, 64);
            unsigned l3 = __shfl((int)plo, k + 3, 64); unsigned v3 = __shfl((int)phi, k + 3, 64);
            float g0 = h[(l0 & 0x1FFFF) * N_CH + lane];
            float g1 = h[(l1 & 0x1FFFF) * N_CH + lane];
            float g2 = h[(l2 & 0x1FFFF) * N_CH + lane];
            float g3 = h[(l3 & 0x1FFFF) * N_CH + lane];
            atomicAdd(&acc[(l0 >> 17) & (BROWS - 1)][lane], __uint_as_float(v0) * g0);
            atomicAdd(&acc[(l1 >> 17) & (BROWS - 1)][lane], __uint_as_float(v1) * g1);
            atomicAdd(&acc[(l2 >> 17) & (BROWS - 1)][lane], __uint_as_float(v2) * g2);
            atomicAdd(&acc[(l3 >> 17) & (BROWS - 1)][lane], __uint_as_float(v3) * g3);
        }
    }
    __syncthreads();

    size_t obase = (size_t)blockIdx.x * BROWS * N_CH;
    for (int i = tid; i < BROWS * N_CH; i += 256) {
        size_t oi = obase + i;
        if (oi < (size_t)N_NODES * N_CH) {
            float x = accf[i] + skip[i & (N_CH - 1)];
            float neg = SELU_SCALE * SELU_ALPHA * expm1f(x);
            out[oi] = x > 0.f ? SELU_SCALE * x : neg;
        }
    }
}

// ===========================================================================
// Fallback path (tiny ws): Round-0 atomic version
// ===========================================================================
__global__ __launch_bounds__(256) void gemm_only_kernel(
    const float* __restrict__ feat, const float* __restrict__ W,
    const float* __restrict__ bias, float* __restrict__ h)
{
    gemm_body(blockIdx.x, feat, W, bias, h);
}

__global__ __launch_bounds__(256) void init_out_kernel(
    float* __restrict__ out, const float* __restrict__ skip)
{
    int idx = blockIdx.x * 256 + threadIdx.x;
    if (idx < N_NODES * N_CH) out[idx] = skip[idx & (N_CH - 1)];
}

__global__ __launch_bounds__(256) void edge_kernel(
    const float* __restrict__ vals, const int* __restrict__ rows,
    const int* __restrict__ cols, const float* __restrict__ h,
    float* __restrict__ out)
{
    int e = blockIdx.x * 4 + (threadIdx.x >> 6);
    int lane = threadIdx.x & 63;
    if (e >= N_EDGES) return;
    int row = rows[e];
    int col = cols[e];
    float v = vals[e];
    atomicAdd(&out[row * N_CH + lane], v * h[col * N_CH + lane]);
}

__global__ __launch_bounds__(256) void selu_kernel(float* __restrict__ out)
{
    int idx = blockIdx.x * 256 + threadIdx.x;
    if (idx >= N_NODES * N_CH) return;
    float x = out[idx];
    float neg = SELU_SCALE * SELU_ALPHA * expm1f(x);
    out[idx] = x > 0.f ? SELU_SCALE * x : neg;
}

// ===========================================================================
static inline size_t align256(size_t x) { return (x + 255) & ~(size_t)255; }

extern "C" void kernel_launch(void* const* d_in, const int* in_sizes, int n_in,
                              void* d_out, int out_size, void* d_ws, size_t ws_size,
                              hipStream_t stream)
{
    const float* features = (const float*)d_in[0];
    const float* W        = (const float*)d_in[1];
    const float* bias     = (const float*)d_in[2];
    const float* skip     = (const float*)d_in[3];
    const float* adj_vals = (const float*)d_in[4];
    const int*   adj_rows = (const int*)d_in[5];
    const int*   adj_cols = (const int*)d_in[6];
    float* out = (float*)d_out;

    // ---- workspace carve-up ----
    char* ws = (char*)d_ws;
    size_t off = 0;
    float* h   = (float*)(ws + off);              off = align256(off + (size_t)N_NODES * N_CH * 4);
    int* bcount  = (int*)(ws + off);              off = align256(off + (size_t)NBUCK * 4);
    int* bstart  = (int*)(ws + off);              off = align256(off + (size_t)(NBUCK + 1) * 4);
    int* gcursor = (int*)(ws + off);              off = align256(off + (size_t)NBUCK * 4);
    unsigned long long* pack = (unsigned long long*)(ws + off);
    off = align256(off + (size_t)N_EDGES * 8);
    size_t need = off;

    if (ws_size >= need) {
        // ---- main path: 128-row bucket binning ----
        zero_bcount_kernel<<<1, 256, 0, stream>>>(bcount);
        hist_kernel<<<BIN_BLOCKS, 256, 0, stream>>>(adj_rows, bcount);
        scan_buckets_kernel<<<1, 1024, 0, stream>>>(bcount, bstart, gcursor);
        binscatter_gemm_kernel<<<BIN_BLOCKS + NB_GEMM, 256, 0, stream>>>(
            adj_rows, adj_cols, adj_vals, gcursor, pack,
            features, W, bias, h);
        bucket_agg_kernel<<<NBUCK, 256, 0, stream>>>(bstart, pack, h, skip, out);
    } else {
        // ---- fallback: atomic scatter ----
        gemm_only_kernel<<<NB_GEMM, 256, 0, stream>>>(features, W, bias, h);
        init_out_kernel<<<(N_NODES * N_CH + 255) / 256, 256, 0, stream>>>(out, skip);
        edge_kernel<<<(N_EDGES + 3) / 4, 256, 0, stream>>>(
            adj_vals, adj_rows, adj_cols, h, out);
        selu_kernel<<<(N_NODES * N_CH + 255) / 256, 256, 0, stream>>>(out);
    }
}

// Round 12
// 301.831 us; speedup vs baseline: 3.0376x; 3.0376x over previous
//
#include <hip/hip_runtime.h>
#include <math.h>

#define N_NODES   100000
#define N_EDGES   1600000
#define D_FEAT    64
#define N_CH      64

#define SELU_SCALE 1.0507009873554805f
#define SELU_ALPHA 1.6732632423543772f

// ------------------------- scan config -------------------------
#define SCAN_TPB   256
#define SCAN_ELEMS 1024                                   // 4 per thread
#define SCAN_NB    ((N_NODES + SCAN_ELEMS - 1) / SCAN_ELEMS)   // 98

// ------------------------- gemm config -------------------------
#define G_ROWS_PER_WAVE 16
#define G_ROWS_PER_BLOCK (4 * G_ROWS_PER_WAVE)   // 64
#define NB_GEMM  ((N_NODES + G_ROWS_PER_BLOCK - 1) / G_ROWS_PER_BLOCK)  // 1563
#define NB_SCAT4 ((N_EDGES / 4 + 255) / 256)     // 1563 (4 edges per thread)

// ---- bf16 helpers (no type deps: raw ushort bits) ----
__device__ __forceinline__ unsigned short f2bf_rne(float x)
{
    unsigned b = __float_as_uint(x);
    unsigned r = (b + 0x7FFFu + ((b >> 16) & 1u)) >> 16;   // round-nearest-even
    return (unsigned short)r;
}
__device__ __forceinline__ float bf2f(unsigned short u)
{
    return __uint_as_float(((unsigned)u) << 16);
}

// ===========================================================================
// GEMM body: h_bf = bf16(features @ W + bias).  Lane = channel; W column in
// 64 VGPRs; feature row via wave-uniform scalar loads.
// ===========================================================================
__device__ __forceinline__ void gemm_body_bf16(
    int gb,
    const float* __restrict__ feat,
    const float* __restrict__ W,
    const float* __restrict__ bias,
    unsigned short* __restrict__ h_bf)
{
    int lane = threadIdx.x & 63;
    int wave = threadIdx.x >> 6;

    float Wc[D_FEAT];
    #pragma unroll
    for (int k = 0; k < D_FEAT; ++k) Wc[k] = W[k * N_CH + lane];
    float b = bias[lane];

    int row0 = (gb * 4 + wave) * G_ROWS_PER_WAVE;
    for (int r = 0; r < G_ROWS_PER_WAVE; ++r) {
        int row = row0 + r;
        if (row >= N_NODES) return;
        int row_u = __builtin_amdgcn_readfirstlane(row);
        const float* frow = feat + (size_t)row_u * D_FEAT;
        float a0 = b, a1 = 0.f, a2 = 0.f, a3 = 0.f;
        #pragma unroll
        for (int k = 0; k < D_FEAT; k += 4) {
            a0 = fmaf(frow[k + 0], Wc[k + 0], a0);
            a1 = fmaf(frow[k + 1], Wc[k + 1], a1);
            a2 = fmaf(frow[k + 2], Wc[k + 2], a2);
            a3 = fmaf(frow[k + 3], Wc[k + 3], a3);
        }
        h_bf[row * N_CH + lane] = f2bf_rne((a0 + a1) + (a2 + a3));
    }
}

// ===========================================================================
// Fused head: degree histogram + per-edge rank (atomic return)  ||  GEMM.
// Both are dependency-free; degree_rank is atomic-latency-bound with idle
// VALU -> GEMM hides under it.
// ===========================================================================
__global__ __launch_bounds__(256) void zero_deg_kernel(int* __restrict__ deg)
{
    int i = blockIdx.x * 256 + threadIdx.x;
    if (i < N_NODES) deg[i] = 0;
}

__global__ __launch_bounds__(256) void degree_rank_gemm_kernel(
    const int* __restrict__ rows, int* __restrict__ deg, int* __restrict__ rank,
    const float* __restrict__ feat, const float* __restrict__ W,
    const float* __restrict__ bias, unsigned short* __restrict__ h_bf)
{
    if (blockIdx.x < NB_SCAT4) {
        int i = blockIdx.x * 256 + threadIdx.x;
        if (i < N_EDGES / 4) {
            const int4 r = reinterpret_cast<const int4*>(rows)[i];
            int4 k;
            k.x = atomicAdd(&deg[r.x], 1);
            k.y = atomicAdd(&deg[r.y], 1);
            k.z = atomicAdd(&deg[r.z], 1);
            k.w = atomicAdd(&deg[r.w], 1);
            reinterpret_cast<int4*>(rank)[i] = k;
        }
    } else {
        gemm_body_bf16(blockIdx.x - NB_SCAT4, feat, W, bias, h_bf);
    }
}

// ===========================================================================
// Exclusive scan of deg -> row_start (3 kernels)
// ===========================================================================
__global__ __launch_bounds__(SCAN_TPB) void scan1_kernel(
    const int* __restrict__ deg, int* __restrict__ row_start,
    int* __restrict__ partials)
{
    __shared__ int lds[SCAN_TPB];
    int t = threadIdx.x;
    int base = blockIdx.x * SCAN_ELEMS + t * 4;
    int v0 = (base + 0 < N_NODES) ? deg[base + 0] : 0;
    int v1 = (base + 1 < N_NODES) ? deg[base + 1] : 0;
    int v2 = (base + 2 < N_NODES) ? deg[base + 2] : 0;
    int v3 = (base + 3 < N_NODES) ? deg[base + 3] : 0;
    int s1 = v0, s2 = v0 + v1, s3 = v0 + v1 + v2, tot = v0 + v1 + v2 + v3;
    lds[t] = tot;
    __syncthreads();
    for (int off = 1; off < SCAN_TPB; off <<= 1) {
        int y = (t >= off) ? lds[t - off] : 0;
        __syncthreads();
        lds[t] += y;
        __syncthreads();
    }
    int texcl = (t > 0) ? lds[t - 1] : 0;
    if (t == SCAN_TPB - 1) partials[blockIdx.x] = lds[SCAN_TPB - 1];
    if (base + 0 < N_NODES) row_start[base + 0] = texcl;
    if (base + 1 < N_NODES) row_start[base + 1] = texcl + s1;
    if (base + 2 < N_NODES) row_start[base + 2] = texcl + s2;
    if (base + 3 < N_NODES) row_start[base + 3] = texcl + s3;
}

__global__ __launch_bounds__(128) void scan2_kernel(int* __restrict__ partials)
{
    __shared__ int lds[128];
    int t = threadIdx.x;
    lds[t] = (t < SCAN_NB) ? partials[t] : 0;
    __syncthreads();
    for (int off = 1; off < 128; off <<= 1) {
        int y = (t >= off) ? lds[t - off] : 0;
        __syncthreads();
        lds[t] += y;
        __syncthreads();
    }
    if (t < SCAN_NB) partials[t] = (t > 0) ? lds[t - 1] : 0;
}

__global__ __launch_bounds__(SCAN_TPB) void scan3_kernel(
    int* __restrict__ row_start, const int* __restrict__ partials)
{
    int t = threadIdx.x;
    int add = partials[blockIdx.x];
    int base = blockIdx.x * SCAN_ELEMS + t * 4;
    #pragma unroll
    for (int j = 0; j < 4; ++j) {
        int idx = base + j;
        if (idx < N_NODES) row_start[idx] += add;
    }
    if (blockIdx.x == 0 && t == 0) row_start[N_NODES] = N_EDGES;
}

// ===========================================================================
// Non-atomic CSR scatter of PACKED (col,val) 8B records (standalone).
// ===========================================================================
__global__ __launch_bounds__(256) void scatter_pack_kernel(
    const int* __restrict__ rows, const int* __restrict__ rank,
    const int* __restrict__ cols, const float* __restrict__ vals,
    const int* __restrict__ row_start, unsigned long long* __restrict__ pack64)
{
    int i = blockIdx.x * 256 + threadIdx.x;
    if (i < N_EDGES / 4) {
        const int4   r  = reinterpret_cast<const int4*>(rows)[i];
        const int4   rk = reinterpret_cast<const int4*>(rank)[i];
        const int4   c  = reinterpret_cast<const int4*>(cols)[i];
        const float4 v  = reinterpret_cast<const float4*>(vals)[i];
        unsigned long long p0 =
            ((unsigned long long)__float_as_uint(v.x) << 32) | (unsigned)c.x;
        unsigned long long p1 =
            ((unsigned long long)__float_as_uint(v.y) << 32) | (unsigned)c.y;
        unsigned long long p2 =
            ((unsigned long long)__float_as_uint(v.z) << 32) | (unsigned)c.z;
        unsigned long long p3 =
            ((unsigned long long)__float_as_uint(v.w) << 32) | (unsigned)c.w;
        __builtin_nontemporal_store(p0, &pack64[row_start[r.x] + rk.x]);
        __builtin_nontemporal_store(p1, &pack64[row_start[r.y] + rk.y]);
        __builtin_nontemporal_store(p2, &pack64[row_start[r.z] + rk.z]);
        __builtin_nontemporal_store(p3, &pack64[row_start[r.w] + rk.w]);
    }
}

// ===========================================================================
// Aggregate: TWO rows per wave, lane = channel, bf16 h gathers (128B/wave).
// 2-deep chain: pack[j] -> h_bf[col].  Fused skip+SeLU epilogue (fp32 acc).
// ===========================================================================
__global__ __launch_bounds__(256) void aggregate_pack_kernel(
    const int*   __restrict__ row_start,
    const uint2* __restrict__ pack,
    const unsigned short* __restrict__ h_bf,
    const float* __restrict__ skip,
    float*       __restrict__ out)
{
    int pair = blockIdx.x * 4 + (threadIdx.x >> 6);   // wave id = row pair
    int lane = threadIdx.x & 63;
    int r0 = pair * 2;
    if (r0 >= N_NODES) return;
    int r1 = r0 + 1;                                  // N_NODES even -> valid

    int s0 = row_start[r0], e0 = row_start[r0 + 1];
    int s1 = row_start[r1], e1 = row_start[r1 + 1];
    float skp = skip[lane];

    float a0 = 0.f, a1 = 0.f, a2 = 0.f, a3 = 0.f;   // row0 chains
    float b0 = 0.f, b1 = 0.f, b2 = 0.f, b3 = 0.f;   // row1 chains

    int j0 = s0, j1 = s1;
    while (j0 < e0 || j1 < e1) {
        int cnt0 = e0 - j0; cnt0 = cnt0 < 0 ? 0 : (cnt0 > 64 ? 64 : cnt0);
        int cnt1 = e1 - j1; cnt1 = cnt1 < 0 ? 0 : (cnt1 > 64 ? 64 : cnt1);
        uint2 p0 = make_uint2(0u, 0u), p1 = make_uint2(0u, 0u);
        if (lane < cnt0) p0 = pack[j0 + lane];        // coalesced 512B
        if (lane < cnt1) p1 = pack[j1 + lane];
        int pc = cnt0 > cnt1 ? cnt0 : cnt1;
        pc = (pc + 3) & ~3;
        for (int k = 0; k < pc; k += 4) {
            // v=0 padding (zero-init p) -> fma contributes 0 for dead slots
            int   c00 = __shfl((int)p0.x, k + 0, 64); float v00 = __shfl(__uint_as_float(p0.y), k + 0, 64);
            int   c10 = __shfl((int)p1.x, k + 0, 64); float v10 = __shfl(__uint_as_float(p1.y), k + 0, 64);
            int   c01 = __shfl((int)p0.x, k + 1, 64); float v01 = __shfl(__uint_as_float(p0.y), k + 1, 64);
            int   c11 = __shfl((int)p1.x, k + 1, 64); float v11 = __shfl(__uint_as_float(p1.y), k + 1, 64);
            int   c02 = __shfl((int)p0.x, k + 2, 64); float v02 = __shfl(__uint_as_float(p0.y), k + 2, 64);
            int   c12 = __shfl((int)p1.x, k + 2, 64); float v12 = __shfl(__uint_as_float(p1.y), k + 2, 64);
            int   c03 = __shfl((int)p0.x, k + 3, 64); float v03 = __shfl(__uint_as_float(p0.y), k + 3, 64);
            int   c13 = __shfl((int)p1.x, k + 3, 64); float v13 = __shfl(__uint_as_float(p1.y), k + 3, 64);
            float g00 = bf2f(h_bf[c00 * N_CH + lane]);
            float g10 = bf2f(h_bf[c10 * N_CH + lane]);
            float g01 = bf2f(h_bf[c01 * N_CH + lane]);
            float g11 = bf2f(h_bf[c11 * N_CH + lane]);
            float g02 = bf2f(h_bf[c02 * N_CH + lane]);
            float g12 = bf2f(h_bf[c12 * N_CH + lane]);
            float g03 = bf2f(h_bf[c03 * N_CH + lane]);
            float g13 = bf2f(h_bf[c13 * N_CH + lane]);
            a0 = fmaf(v00, g00, a0);
            b0 = fmaf(v10, g10, b0);
            a1 = fmaf(v01, g01, a1);
            b1 = fmaf(v11, g11, b1);
            a2 = fmaf(v02, g02, a2);
            b2 = fmaf(v12, g12, b2);
            a3 = fmaf(v03, g03, a3);
            b3 = fmaf(v13, g13, b3);
        }
        j0 += 64; j1 += 64;
    }
    float x0 = (a0 + a1) + (a2 + a3) + skp;
    float x1 = (b0 + b1) + (b2 + b3) + skp;
    float n0 = SELU_SCALE * SELU_ALPHA * expm1f(x0);
    float n1 = SELU_SCALE * SELU_ALPHA * expm1f(x1);
    out[r0 * N_CH + lane] = x0 > 0.f ? SELU_SCALE * x0 : n0;
    out[r1 * N_CH + lane] = x1 > 0.f ? SELU_SCALE * x1 : n1;
}

// ===========================================================================
// Fallback path (tiny ws): Round-0 atomic version (fp32 h)
// ===========================================================================
__global__ __launch_bounds__(256) void gemm_only_kernel(
    const float* __restrict__ feat, const float* __restrict__ W,
    const float* __restrict__ bias, float* __restrict__ h)
{
    int lane = threadIdx.x & 63;
    int wave = threadIdx.x >> 6;
    float Wc[D_FEAT];
    #pragma unroll
    for (int k = 0; k < D_FEAT; ++k) Wc[k] = W[k * N_CH + lane];
    float b = bias[lane];
    int row0 = (blockIdx.x * 4 + wave) * G_ROWS_PER_WAVE;
    for (int r = 0; r < G_ROWS_PER_WAVE; ++r) {
        int row = row0 + r;
        if (row >= N_NODES) return;
        int row_u = __builtin_amdgcn_readfirstlane(row);
        const float* frow = feat + (size_t)row_u * D_FEAT;
        float a0 = b, a1 = 0.f, a2 = 0.f, a3 = 0.f;
        #pragma unroll
        for (int k = 0; k < D_FEAT; k += 4) {
            a0 = fmaf(frow[k + 0], Wc[k + 0], a0);
            a1 = fmaf(frow[k + 1], Wc[k + 1], a1);
            a2 = fmaf(frow[k + 2], Wc[k + 2], a2);
            a3 = fmaf(frow[k + 3], Wc[k + 3], a3);
        }
        h[row * N_CH + lane] = (a0 + a1) + (a2 + a3);
    }
}

__global__ __launch_bounds__(256) void init_out_kernel(
    float* __restrict__ out, const float* __restrict__ skip)
{
    int idx = blockIdx.x * 256 + threadIdx.x;
    if (idx < N_NODES * N_CH) out[idx] = skip[idx & (N_CH - 1)];
}

__global__ __launch_bounds__(256) void edge_kernel(
    const float* __restrict__ vals, const int* __restrict__ rows,
    const int* __restrict__ cols, const float* __restrict__ h,
    float* __restrict__ out)
{
    int e = blockIdx.x * 4 + (threadIdx.x >> 6);
    int lane = threadIdx.x & 63;
    if (e >= N_EDGES) return;
    int row = rows[e];
    int col = cols[e];
    float v = vals[e];
    atomicAdd(&out[row * N_CH + lane], v * h[col * N_CH + lane]);
}

__global__ __launch_bounds__(256) void selu_kernel(float* __restrict__ out)
{
    int idx = blockIdx.x * 256 + threadIdx.x;
    if (idx >= N_NODES * N_CH) return;
    float x = out[idx];
    float neg = SELU_SCALE * SELU_ALPHA * expm1f(x);
    out[idx] = x > 0.f ? SELU_SCALE * x : neg;
}

// ===========================================================================
static inline size_t align256(size_t x) { return (x + 255) & ~(size_t)255; }

extern "C" void kernel_launch(void* const* d_in, const int* in_sizes, int n_in,
                              void* d_out, int out_size, void* d_ws, size_t ws_size,
                              hipStream_t stream)
{
    const float* features = (const float*)d_in[0];
    const float* W        = (const float*)d_in[1];
    const float* bias     = (const float*)d_in[2];
    const float* skip     = (const float*)d_in[3];
    const float* adj_vals = (const float*)d_in[4];
    const int*   adj_rows = (const int*)d_in[5];
    const int*   adj_cols = (const int*)d_in[6];
    float* out = (float*)d_out;

    // ---- workspace carve-up ----
    char* ws = (char*)d_ws;
    size_t off = 0;
    unsigned short* h_bf = (unsigned short*)(ws + off);
    off = align256(off + (size_t)N_NODES * N_CH * 2);               // 12.8 MB
    int* row_start = (int*)(ws + off);  off = align256(off + (size_t)(N_NODES + 1) * 4);
    int* deg       = (int*)(ws + off);  off = align256(off + (size_t)N_NODES * 4);
    int* partials  = (int*)(ws + off);  off = align256(off + 128 * 4);
    int* rank      = (int*)(ws + off);  off = align256(off + (size_t)N_EDGES * 4);
    unsigned long long* pack64 = (unsigned long long*)(ws + off);
    uint2* pack = (uint2*)(ws + off);
    size_t need = off + align256((size_t)N_EDGES * 8);

    if (ws_size >= need) {
        // ---- main path: bf16-h packed CSR ----
        zero_deg_kernel<<<(N_NODES + 255) / 256, 256, 0, stream>>>(deg);
        // degree+rank || GEMM (both dependency-free heads)
        degree_rank_gemm_kernel<<<NB_SCAT4 + NB_GEMM, 256, 0, stream>>>(
            adj_rows, deg, rank, features, W, bias, h_bf);
        scan1_kernel<<<SCAN_NB, SCAN_TPB, 0, stream>>>(deg, row_start, partials);
        scan2_kernel<<<1, 128, 0, stream>>>(partials);
        scan3_kernel<<<SCAN_NB, SCAN_TPB, 0, stream>>>(row_start, partials);
        scatter_pack_kernel<<<NB_SCAT4, 256, 0, stream>>>(
            adj_rows, rank, adj_cols, adj_vals, row_start, pack64);
        aggregate_pack_kernel<<<(N_NODES / 2 + 3) / 4, 256, 0, stream>>>(
            row_start, pack, h_bf, skip, out);
    } else {
        // ---- fallback: atomic scatter (fp32 h in ws head) ----
        float* h = (float*)d_ws;
        gemm_only_kernel<<<NB_GEMM, 256, 0, stream>>>(features, W, bias, h);
        init_out_kernel<<<(N_NODES * N_CH + 255) / 256, 256, 0, stream>>>(out, skip);
        edge_kernel<<<(N_EDGES + 3) / 4, 256, 0, stream>>>(
            adj_vals, adj_rows, adj_cols, h, out);
        selu_kernel<<<(N_NODES * N_CH + 255) / 256, 256, 0, stream>>>(out);
    }
}